// Round 4
// baseline (159.042 us; speedup 1.0000x reference)
//
#include <hip/hip_runtime.h>
#include <math.h>

#define B_ 1024
#define F_ 39
#define K_ 16
#define P_ 741
#define T_ 9139
#define NC_ 9880          // P_ + T_
#define EPS_ 1e-3f
#define S2 20             // LDS stride in bf16 elems for emb/Y rows: slot=(5f+j)%16, conflict-free
#define LS2 9920          // levels row stride in bf16 elems (19840 B)

__device__ __forceinline__ unsigned short to_bf16(float x) {
    unsigned u = __float_as_uint(x);
    u += 0x7fffu + ((u >> 16) & 1u);   // round-to-nearest-even
    return (unsigned short)(u >> 16);
}
__device__ __forceinline__ float from_bf16(unsigned short h) {
    return __uint_as_float(((unsigned)h) << 16);
}
__device__ __forceinline__ float2 bf2x(unsigned u) {   // [lo|hi] packed bf16 -> 2 floats
    return make_float2(__uint_as_float(u << 16), __uint_as_float(u & 0xffff0000u));
}

// ---------- kernel 0: zero stats buffers + pack column indices ----------------------
// pairs  (c < P_):  pk = (cols[c]*S2) | (rows[c]*S2)<<10      (both <= 760, 10 bits)
// triples(c >= P_): pk = pair_idx(i1,i2) | (i3*S2)<<10        (pair_idx <= 740)
__global__ __launch_bounds__(256) void prep_k(const int* __restrict__ rows,
                                              const int* __restrict__ cols,
                                              const int* __restrict__ i1,
                                              const int* __restrict__ i2,
                                              const int* __restrict__ i3,
                                              unsigned* __restrict__ pidx,
                                              float* __restrict__ colsum,
                                              float* __restrict__ colsumsq,
                                              float* __restrict__ Cacc) {
    int c = blockIdx.x * 256 + threadIdx.x;
    if (c >= NC_) return;
    colsum[c] = 0.f;
    colsumsq[c] = 0.f;
    if (c == 0) Cacc[0] = 0.f;
    unsigned pk;
    if (c < P_) {
        pk = (unsigned)(cols[c] * S2) | ((unsigned)(rows[c] * S2) << 10);
    } else {
        int t = c - P_;
        int a = i1[t], b = i2[t], cc = i3[t];
        int p = a * (2 * F_ - 1 - a) / 2 + (b - a - 1);   // lex pair index of (a,b)
        pk = (unsigned)p | ((unsigned)(cc * S2) << 10);
    }
    pidx[c] = pk;
}

// ---------- kernel 1: fused gather + pair products + all level values (bf16) --------
// 512 blocks x 2 batch rows each; 512 threads. emb/Y packed bf16 in LDS.
__global__ __launch_bounds__(512) void levels_k(const int* __restrict__ feats,
                                                const float* __restrict__ v,
                                                const unsigned* __restrict__ pidx,
                                                unsigned short* __restrict__ levels) {
    int tid = threadIdx.x;
    __shared__ int tok[F_];
    __shared__ __attribute__((aligned(16))) unsigned short emb2[F_ * S2];   // 1560 B
    __shared__ __attribute__((aligned(16))) unsigned short Y2[P_ * S2];     // 29640 B
    __shared__ __attribute__((aligned(16))) unsigned short buf[LS2];        // 19840 B

#pragma unroll 1
    for (int rr = 0; rr < 2; ++rr) {
        int b = 2 * blockIdx.x + rr;
        __syncthreads();                       // protect LDS from previous iteration
        if (tid < F_) tok[tid] = feats[b * F_ + tid];
        __syncthreads();
        for (int idx = tid; idx < F_ * K_; idx += 512) {
            int f = idx >> 4, k = idx & 15;
            emb2[f * S2 + k] = to_bf16(v[(size_t)tok[f] * K_ + k]);
        }
        __syncthreads();

        // P0: all 741 pair products -> Y2 (bf16), level2 = sum_k
#pragma unroll 1
        for (int p = tid; p < P_; p += 512) {
            unsigned pk = pidx[p];
            int o1 = (int)(pk & 1023u);
            int o2 = (int)((pk >> 10) & 1023u);
            float s = 0.f;
#pragma unroll
            for (int j = 0; j < 4; ++j) {
                uint2 ua = *(const uint2*)&emb2[o1 + 4 * j];
                uint2 uc = *(const uint2*)&emb2[o2 + 4 * j];
                float2 a0 = bf2x(ua.x), a1 = bf2x(ua.y);
                float2 c0 = bf2x(uc.x), c1 = bf2x(uc.y);
                float y0 = a0.x * c0.x, y1 = a0.y * c0.y;
                float y2 = a1.x * c1.x, y3 = a1.y * c1.y;
                s += y0 + y1 + y2 + y3;
                uint2 pk2;
                pk2.x = (unsigned)to_bf16(y0) | ((unsigned)to_bf16(y1) << 16);
                pk2.y = (unsigned)to_bf16(y2) | ((unsigned)to_bf16(y3) << 16);
                *(uint2*)&Y2[p * S2 + 4 * j] = pk2;
            }
            buf[p] = to_bf16(s);
        }
        __syncthreads();

        // P1: triples, branch-free: x = <Y2[p], emb2[i3]>
#pragma unroll 1
        for (int i = 0; i < (T_ + 511) / 512; ++i) {
            int t = i * 512 + tid;
            if (t < T_) {
                unsigned pk = pidx[P_ + t];
                int p  = (int)(pk & 1023u);
                int o3 = (int)((pk >> 10) & 1023u);
                int yb = p * S2;
                float s = 0.f;
#pragma unroll
                for (int j = 0; j < 4; ++j) {
                    uint2 uy = *(const uint2*)&Y2[yb + 4 * j];
                    uint2 ue = *(const uint2*)&emb2[o3 + 4 * j];
                    float2 y0 = bf2x(uy.x), y1 = bf2x(uy.y);
                    float2 e0 = bf2x(ue.x), e1 = bf2x(ue.y);
                    s += y0.x * e0.x + y0.y * e0.y + y1.x * e1.x + y1.y * e1.y;
                }
                buf[P_ + t] = to_bf16(s);
            }
        }
        if (tid < LS2 - NC_) buf[NC_ + tid] = 0;   // pad tail
        __syncthreads();

        // coalesced flush: 19840 B = 1240 uint4
        uint4* dst = (uint4*)(levels + (size_t)b * LS2);
        const uint4* src = (const uint4*)buf;
        for (int idx = tid; idx < LS2 / 8; idx += 512)
            dst[idx] = src[idx];
    }
}

// ---------- kernel 2: column stats over bf16 levels ---------------------------------
__global__ __launch_bounds__(256) void stats2_k(const unsigned short* __restrict__ levels,
                                                float* __restrict__ colsum,
                                                float* __restrict__ colsumsq) {
    int col = blockIdx.x * 256 + threadIdx.x;
    if (col >= NC_) return;
    const unsigned short* p = levels + (size_t)(blockIdx.y * 16) * LS2 + col;
    float s1 = 0.f, s2 = 0.f;
#pragma unroll
    for (int r = 0; r < 16; ++r) {
        float x = from_bf16(p[(size_t)r * LS2]);
        s1 += x;
        s2 += x * x;
    }
    atomicAdd(&colsum[col], s1);
    atomicAdd(&colsumsq[col], s2);
}

// ---------- kernel 3: BN finalize -> per-column scale + scalar C --------------------
__global__ __launch_bounds__(256) void finalize_k(const float* __restrict__ colsum,
                                                  const float* __restrict__ colsumsq,
                                                  const float* __restrict__ gamma2,
                                                  const float* __restrict__ beta2,
                                                  const float* __restrict__ gw2,
                                                  const float* __restrict__ gamma3,
                                                  const float* __restrict__ beta3,
                                                  const float* __restrict__ gw3,
                                                  float* __restrict__ scale,
                                                  float* __restrict__ Cacc) {
    int col = blockIdx.x * 256 + threadIdx.x;
    float c = 0.f;
    if (col < NC_) {
        float mean = colsum[col] * (1.0f / B_);
        float var  = colsumsq[col] * (1.0f / B_) - mean * mean;
        float inv  = 1.0f / sqrtf(var + EPS_);
        float g, be, gw;
        if (col < P_) {
            g = gamma2[col]; be = beta2[col]; gw = gw2[col];
        } else {
            int t = col - P_;
            g = gamma3[t]; be = beta3[t]; gw = gw3[t];
        }
        scale[col] = gw * g * inv;
        c = gw * (be - g * inv * mean);
    }
    __shared__ float red[256];
    red[threadIdx.x] = c;
    __syncthreads();
    for (int s = 128; s > 0; s >>= 1) {
        if (threadIdx.x < s) red[threadIdx.x] += red[threadIdx.x + s];
        __syncthreads();
    }
    if (threadIdx.x == 0) atomicAdd(Cacc, red[0]);
}

// ---------- kernel 4: weighted row sum + linear term -> logits ----------------------
__global__ __launch_bounds__(256) void out_k(const unsigned short* __restrict__ levels,
                                             const float* __restrict__ scale,
                                             const int* __restrict__ feats,
                                             const float* __restrict__ w,
                                             const float* __restrict__ Cacc,
                                             const float* __restrict__ bias,
                                             float* __restrict__ out) {
    int b = blockIdx.x, tid = threadIdx.x;
    const uint2* lv = (const uint2*)(levels + (size_t)b * LS2);   // 4 bf16 per uint2
    float acc = 0.f;
    // 9880 bf16 = 2470 uint2 exactly
    for (int idx = tid; idx < 2470; idx += 256) {
        uint2 u = lv[idx];
        int cbase = idx * 4;
        float4 sc = *(const float4*)&scale[cbase];
        float x0 = __uint_as_float(u.x << 16);
        float x1 = __uint_as_float(u.x & 0xffff0000u);
        float x2 = __uint_as_float(u.y << 16);
        float x3 = __uint_as_float(u.y & 0xffff0000u);
        acc += sc.x * x0 + sc.y * x1 + sc.z * x2 + sc.w * x3;
    }
    if (tid < F_) acc += w[feats[b * F_ + tid]];   // linear term
    __shared__ float red[256];
    red[tid] = acc;
    __syncthreads();
    for (int s = 128; s > 0; s >>= 1) {
        if (tid < s) red[tid] += red[tid + s];
        __syncthreads();
    }
    if (tid == 0) out[b] = red[0] + Cacc[0] + bias[0];
}

// ---------- host launcher -----------------------------------------------------------
extern "C" void kernel_launch(void* const* d_in, const int* in_sizes, int n_in,
                              void* d_out, int out_size, void* d_ws, size_t ws_size,
                              hipStream_t stream) {
    const int*   feats  = (const int*)d_in[0];
    const float* w      = (const float*)d_in[1];
    const float* v      = (const float*)d_in[2];
    const float* bias   = (const float*)d_in[3];
    const float* gamma2 = (const float*)d_in[4];
    const float* beta2  = (const float*)d_in[5];
    const float* gw2    = (const float*)d_in[6];
    const float* gamma3 = (const float*)d_in[7];
    const float* beta3  = (const float*)d_in[8];
    const float* gw3    = (const float*)d_in[9];
    const int*   rows   = (const int*)d_in[10];
    const int*   cols   = (const int*)d_in[11];
    const int*   i1     = (const int*)d_in[12];
    const int*   i2     = (const int*)d_in[13];
    const int*   i3     = (const int*)d_in[14];
    float*       out    = (float*)d_out;
    float*       ws     = (float*)d_ws;

    // workspace layout (float offsets)
    float*          scale    = ws;                    // 9880
    float*          colsum   = ws + 9880;             // 9880
    float*          colsumsq = ws + 19760;            // 9880
    float*          Cacc     = ws + 29640;            // 1
    unsigned*       pidx     = (unsigned*)(ws + 29696);       // 9880
    unsigned short* levels   = (unsigned short*)(ws + 39680); // 1024*9920 bf16 (~20.3 MB)

    prep_k<<<(NC_ + 255) / 256, 256, 0, stream>>>(rows, cols, i1, i2, i3,
                                                  pidx, colsum, colsumsq, Cacc);
    levels_k<<<B_ / 2, 512, 0, stream>>>(feats, v, pidx, levels);
    stats2_k<<<dim3((NC_ + 255) / 256, B_ / 16), 256, 0, stream>>>(levels, colsum, colsumsq);
    finalize_k<<<(NC_ + 255) / 256, 256, 0, stream>>>(colsum, colsumsq,
                                                      gamma2, beta2, gw2,
                                                      gamma3, beta3, gw3, scale, Cacc);
    out_k<<<B_, 256, 0, stream>>>(levels, scale, feats, w, Cacc, bias, out);
}

// Round 5
// 126.209 us; speedup vs baseline: 1.2601x; 1.2601x over previous
//
#include <hip/hip_runtime.h>
#include <hip/hip_fp16.h>
#include <math.h>

#define B_ 1024
#define F_ 39
#define K_ 16
#define P_ 741
#define T_ 9139
#define NC_ 9880          // P_ + T_
#define EPS_ 1e-3f
#define YSTR 24           // Y row stride in f16 (48 B: 16B-aligned rows, slot=(3p+q)%8)
#define ESTR 40           // emb row stride in f16 (80 B: slot=(5c+q)%8, 5 coprime 8)
#define LS2 9920          // levels row stride in f16 elems (19840 B, 16B-aligned)

typedef _Float16 half2v __attribute__((ext_vector_type(2)));

__device__ __forceinline__ float hdot2(unsigned a, unsigned b, float acc) {
    half2v ha = __builtin_bit_cast(half2v, a);
    half2v hb = __builtin_bit_cast(half2v, b);
#if __has_builtin(__builtin_amdgcn_fdot2)
    return __builtin_amdgcn_fdot2(ha, hb, acc, false);
#else
    return acc + (float)ha.x * (float)hb.x + (float)ha.y * (float)hb.y;
#endif
}
__device__ __forceinline__ float f16f(unsigned short h) {
    return __half2float(__builtin_bit_cast(__half, h));
}

// ---------- kernel 0: zero stats buffers + pack column indices ----------------------
// pairs  (c < P_):  pk = (cols[c]*ESTR) | (rows[c]*ESTR)<<11    (each <= 1520, 11 bits)
// triples(c >= P_): pk = (pair_idx*YSTR) | (i3*ESTR)<<15        (17760 fits 15 bits)
__global__ __launch_bounds__(256) void prep_k(const int* __restrict__ rows,
                                              const int* __restrict__ cols,
                                              const int* __restrict__ i1,
                                              const int* __restrict__ i2,
                                              const int* __restrict__ i3,
                                              unsigned* __restrict__ pidx,
                                              float* __restrict__ colsum,
                                              float* __restrict__ colsumsq,
                                              float* __restrict__ Cacc) {
    int c = blockIdx.x * 256 + threadIdx.x;
    if (c >= NC_) return;
    colsum[c] = 0.f;
    colsumsq[c] = 0.f;
    if (c == 0) Cacc[0] = 0.f;
    unsigned pk;
    if (c < P_) {
        pk = (unsigned)(cols[c] * ESTR) | ((unsigned)(rows[c] * ESTR) << 11);
    } else {
        int t = c - P_;
        int a = i1[t], b = i2[t], cc = i3[t];
        int p = a * (2 * F_ - 1 - a) / 2 + (b - a - 1);   // lex pair index of (a,b)
        pk = (unsigned)(p * YSTR) | ((unsigned)(cc * ESTR) << 15);
    }
    pidx[c] = pk;
}

// ---------- kernel 1: fused gather + pair products + all level values (f16) ---------
// One batch row per block; 1024 blocks x 512 threads; ~39 KB LDS -> 4 blocks/CU.
__global__ __launch_bounds__(512) void levels_k(const int* __restrict__ feats,
                                                const float* __restrict__ v,
                                                const unsigned* __restrict__ pidx,
                                                unsigned short* __restrict__ levels) {
    int b = blockIdx.x;
    int tid = threadIdx.x;
    __shared__ int tok[F_];
    __shared__ __attribute__((aligned(16))) unsigned short emb2[F_ * ESTR];   // 3120 B
    __shared__ __attribute__((aligned(16))) unsigned short Y2[P_ * YSTR];     // 35568 B

    unsigned short* lrow = levels + (size_t)b * LS2;

    if (tid < F_) tok[tid] = feats[b * F_ + tid];
    __syncthreads();
    for (int idx = tid; idx < F_ * K_; idx += 512) {
        int f = idx >> 4, k = idx & 15;
        emb2[f * ESTR + k] = __builtin_bit_cast(unsigned short,
                                 __float2half(v[(size_t)tok[f] * K_ + k]));
    }
    __syncthreads();

    // P0: all 741 pair products -> Y2 (f16), level2 -> global
#pragma unroll 1
    for (int p = tid; p < P_; p += 512) {
        unsigned pk = pidx[p];
        int o1 = (int)(pk & 2047u);
        int o2 = (int)((pk >> 11) & 2047u);
        uint4 ua0 = *(const uint4*)&emb2[o1];
        uint4 ua1 = *(const uint4*)&emb2[o1 + 8];
        uint4 uc0 = *(const uint4*)&emb2[o2];
        uint4 uc1 = *(const uint4*)&emb2[o2 + 8];
        float s = 0.f;
        uint4 y0, y1;
#define PKMUL(dst, a, c) {                                                    \
        half2v _a = __builtin_bit_cast(half2v, a);                            \
        half2v _c = __builtin_bit_cast(half2v, c);                            \
        half2v _y = _a * _c;                                                  \
        dst = __builtin_bit_cast(unsigned, _y);                               \
        s = hdot2(a, c, s); }
        PKMUL(y0.x, ua0.x, uc0.x); PKMUL(y0.y, ua0.y, uc0.y);
        PKMUL(y0.z, ua0.z, uc0.z); PKMUL(y0.w, ua0.w, uc0.w);
        PKMUL(y1.x, ua1.x, uc1.x); PKMUL(y1.y, ua1.y, uc1.y);
        PKMUL(y1.z, ua1.z, uc1.z); PKMUL(y1.w, ua1.w, uc1.w);
#undef PKMUL
        *(uint4*)&Y2[p * YSTR] = y0;
        *(uint4*)&Y2[p * YSTR + 8] = y1;
        lrow[p] = __builtin_bit_cast(unsigned short, __float2half(s));
    }
    __syncthreads();

    // P1: triples, branch-free: x = <Y2[p], emb2[i3]>, write straight to global
#pragma unroll 3
    for (int i = 0; i < (T_ + 511) / 512; ++i) {
        int t = i * 512 + tid;
        if (t < T_) {
            unsigned pk = pidx[P_ + t];
            int yb = (int)(pk & 32767u);
            int o3 = (int)(pk >> 15);
            uint4 uy0 = *(const uint4*)&Y2[yb];
            uint4 uy1 = *(const uint4*)&Y2[yb + 8];
            uint4 ue0 = *(const uint4*)&emb2[o3];
            uint4 ue1 = *(const uint4*)&emb2[o3 + 8];
            float s = 0.f;
            s = hdot2(uy0.x, ue0.x, s); s = hdot2(uy0.y, ue0.y, s);
            s = hdot2(uy0.z, ue0.z, s); s = hdot2(uy0.w, ue0.w, s);
            s = hdot2(uy1.x, ue1.x, s); s = hdot2(uy1.y, ue1.y, s);
            s = hdot2(uy1.z, ue1.z, s); s = hdot2(uy1.w, ue1.w, s);
            lrow[P_ + t] = __builtin_bit_cast(unsigned short, __float2half(s));
        }
    }
}

// ---------- kernel 2: column stats over f16 levels ----------------------------------
__global__ __launch_bounds__(256) void stats2_k(const unsigned short* __restrict__ levels,
                                                float* __restrict__ colsum,
                                                float* __restrict__ colsumsq) {
    int col = blockIdx.x * 256 + threadIdx.x;
    if (col >= NC_) return;
    const unsigned short* p = levels + (size_t)(blockIdx.y * 16) * LS2 + col;
    float s1 = 0.f, s2 = 0.f;
#pragma unroll
    for (int r = 0; r < 16; ++r) {
        float x = f16f(p[(size_t)r * LS2]);
        s1 += x;
        s2 += x * x;
    }
    atomicAdd(&colsum[col], s1);
    atomicAdd(&colsumsq[col], s2);
}

// ---------- kernel 3: BN finalize -> per-column scale + scalar C --------------------
__global__ __launch_bounds__(256) void finalize_k(const float* __restrict__ colsum,
                                                  const float* __restrict__ colsumsq,
                                                  const float* __restrict__ gamma2,
                                                  const float* __restrict__ beta2,
                                                  const float* __restrict__ gw2,
                                                  const float* __restrict__ gamma3,
                                                  const float* __restrict__ beta3,
                                                  const float* __restrict__ gw3,
                                                  float* __restrict__ scale,
                                                  float* __restrict__ Cacc) {
    int col = blockIdx.x * 256 + threadIdx.x;
    float c = 0.f;
    if (col < NC_) {
        float mean = colsum[col] * (1.0f / B_);
        float var  = colsumsq[col] * (1.0f / B_) - mean * mean;
        float inv  = 1.0f / sqrtf(var + EPS_);
        float g, be, gw;
        if (col < P_) {
            g = gamma2[col]; be = beta2[col]; gw = gw2[col];
        } else {
            int t = col - P_;
            g = gamma3[t]; be = beta3[t]; gw = gw3[t];
        }
        scale[col] = gw * g * inv;
        c = gw * (be - g * inv * mean);
    }
    __shared__ float red[256];
    red[threadIdx.x] = c;
    __syncthreads();
    for (int s = 128; s > 0; s >>= 1) {
        if (threadIdx.x < s) red[threadIdx.x] += red[threadIdx.x + s];
        __syncthreads();
    }
    if (threadIdx.x == 0) atomicAdd(Cacc, red[0]);
}

// ---------- kernel 4: weighted row sum + linear term -> logits ----------------------
__global__ __launch_bounds__(256) void out_k(const unsigned short* __restrict__ levels,
                                             const float* __restrict__ scale,
                                             const int* __restrict__ feats,
                                             const float* __restrict__ w,
                                             const float* __restrict__ Cacc,
                                             const float* __restrict__ bias,
                                             float* __restrict__ out) {
    int b = blockIdx.x, tid = threadIdx.x;
    const uint2* lv = (const uint2*)(levels + (size_t)b * LS2);   // 4 f16 per uint2
    float acc = 0.f;
    // 9880 f16 = 2470 uint2 exactly
    for (int idx = tid; idx < 2470; idx += 256) {
        uint2 u = lv[idx];
        float4 sc = *(const float4*)&scale[idx * 4];
        float2 f0 = __half22float2(__builtin_bit_cast(__half2, u.x));
        float2 f1 = __half22float2(__builtin_bit_cast(__half2, u.y));
        acc += sc.x * f0.x + sc.y * f0.y + sc.z * f1.x + sc.w * f1.y;
    }
    if (tid < F_) acc += w[feats[b * F_ + tid]];   // linear term
    __shared__ float red[256];
    red[tid] = acc;
    __syncthreads();
    for (int s = 128; s > 0; s >>= 1) {
        if (tid < s) red[tid] += red[tid + s];
        __syncthreads();
    }
    if (tid == 0) out[b] = red[0] + Cacc[0] + bias[0];
}

// ---------- host launcher -----------------------------------------------------------
extern "C" void kernel_launch(void* const* d_in, const int* in_sizes, int n_in,
                              void* d_out, int out_size, void* d_ws, size_t ws_size,
                              hipStream_t stream) {
    const int*   feats  = (const int*)d_in[0];
    const float* w      = (const float*)d_in[1];
    const float* v      = (const float*)d_in[2];
    const float* bias   = (const float*)d_in[3];
    const float* gamma2 = (const float*)d_in[4];
    const float* beta2  = (const float*)d_in[5];
    const float* gw2    = (const float*)d_in[6];
    const float* gamma3 = (const float*)d_in[7];
    const float* beta3  = (const float*)d_in[8];
    const float* gw3    = (const float*)d_in[9];
    const int*   rows   = (const int*)d_in[10];
    const int*   cols   = (const int*)d_in[11];
    const int*   i1     = (const int*)d_in[12];
    const int*   i2     = (const int*)d_in[13];
    const int*   i3     = (const int*)d_in[14];
    float*       out    = (float*)d_out;
    float*       ws     = (float*)d_ws;

    // workspace layout (float offsets)
    float*          scale    = ws;                    // 9880
    float*          colsum   = ws + 9880;             // 9880
    float*          colsumsq = ws + 19760;            // 9880
    float*          Cacc     = ws + 29640;            // 1
    unsigned*       pidx     = (unsigned*)(ws + 29696);       // 9880
    unsigned short* levels   = (unsigned short*)(ws + 39680); // 1024*9920 f16 (~20.3 MB)

    prep_k<<<(NC_ + 255) / 256, 256, 0, stream>>>(rows, cols, i1, i2, i3,
                                                  pidx, colsum, colsumsq, Cacc);
    levels_k<<<B_, 512, 0, stream>>>(feats, v, pidx, levels);
    stats2_k<<<dim3((NC_ + 255) / 256, B_ / 16), 256, 0, stream>>>(levels, colsum, colsumsq);
    finalize_k<<<(NC_ + 255) / 256, 256, 0, stream>>>(colsum, colsumsq,
                                                      gamma2, beta2, gw2,
                                                      gamma3, beta3, gw3, scale, Cacc);
    out_k<<<B_, 256, 0, stream>>>(levels, scale, feats, w, Cacc, bias, out);
}

// Round 6
// 123.314 us; speedup vs baseline: 1.2897x; 1.0235x over previous
//
#include <hip/hip_runtime.h>
#include <hip/hip_fp16.h>
#include <math.h>

#define B_ 1024
#define F_ 39
#define K_ 16
#define P_ 741
#define T_ 9139
#define NC_ 9880          // P_ + T_
#define EPS_ 1e-3f
#define YSTR 24           // Y row stride in f16 (48 B: 16B-aligned rows)
#define ESTR 40           // emb row stride in f16 (80 B: b128 slot=(5c)%8, 5 coprime 8)
#define LS2 9920          // levels row stride in f16 elems (19840 B, 16B-aligned)
#define NSPLIT 8          // stats partial splits (128 rows each)

typedef _Float16 half2v __attribute__((ext_vector_type(2)));

__device__ __forceinline__ float hdot2(unsigned a, unsigned b, float acc) {
    half2v ha = __builtin_bit_cast(half2v, a);
    half2v hb = __builtin_bit_cast(half2v, b);
#if __has_builtin(__builtin_amdgcn_fdot2)
    return __builtin_amdgcn_fdot2(ha, hb, acc, false);
#else
    return acc + (float)ha.x * (float)hb.x + (float)ha.y * (float)hb.y;
#endif
}
__device__ __forceinline__ float f16f(unsigned short h) {
    return __half2float(__builtin_bit_cast(__half, h));
}

// ---------- kernel 0: zero Cacc + pack column indices -------------------------------
// pairs  (c < P_):  pk = (cols[c]*ESTR) | (rows[c]*ESTR)<<11    (each <= 1520, 11 bits)
// triples(c >= P_): pk = (pair_idx*YSTR) | (i3*ESTR)<<15        (17760 fits 15 bits)
__global__ __launch_bounds__(256) void prep_k(const int* __restrict__ rows,
                                              const int* __restrict__ cols,
                                              const int* __restrict__ i1,
                                              const int* __restrict__ i2,
                                              const int* __restrict__ i3,
                                              unsigned* __restrict__ pidx,
                                              float* __restrict__ Cacc) {
    int c = blockIdx.x * 256 + threadIdx.x;
    if (c >= NC_) return;
    if (c == 0) Cacc[0] = 0.f;
    unsigned pk;
    if (c < P_) {
        pk = (unsigned)(cols[c] * ESTR) | ((unsigned)(rows[c] * ESTR) << 11);
    } else {
        int t = c - P_;
        int a = i1[t], b = i2[t], cc = i3[t];
        int p = a * (2 * F_ - 1 - a) / 2 + (b - a - 1);   // lex pair index of (a,b)
        pk = (unsigned)(p * YSTR) | ((unsigned)(cc * ESTR) << 15);
    }
    pidx[c] = pk;
}

// ---------- kernel 1: fused gather + pair products + all level values (f16) ---------
// One batch row per block; 1024 blocks x 512 threads; ~39 KB LDS -> 4 blocks/CU.
__global__ __launch_bounds__(512) void levels_k(const int* __restrict__ feats,
                                                const float* __restrict__ v,
                                                const unsigned* __restrict__ pidx,
                                                unsigned short* __restrict__ levels) {
    int b = blockIdx.x;
    int tid = threadIdx.x;
    __shared__ int tok[F_];
    __shared__ __attribute__((aligned(16))) unsigned short emb2[F_ * ESTR];   // 3120 B
    __shared__ __attribute__((aligned(16))) unsigned short Y2[P_ * YSTR];     // 35568 B

    unsigned short* lrow = levels + (size_t)b * LS2;

    // prefetch all column descriptors this thread will need (loads overlap staging/P0)
    unsigned pk_p0 = (tid < P_) ? pidx[tid] : 0u;
    unsigned pk_p1 = (tid + 512 < P_) ? pidx[tid + 512] : 0u;
    unsigned pkt[18];
#pragma unroll
    for (int i = 0; i < 18; ++i) {
        int t = i * 512 + tid;
        pkt[i] = (t < T_) ? pidx[P_ + t] : 0u;
    }

    if (tid < F_) tok[tid] = feats[b * F_ + tid];
    __syncthreads();
    for (int idx = tid; idx < F_ * K_; idx += 512) {
        int f = idx >> 4, k = idx & 15;
        emb2[f * ESTR + k] = __builtin_bit_cast(unsigned short,
                                 __float2half(v[(size_t)tok[f] * K_ + k]));
    }
    __syncthreads();

    // P0: all 741 pair products -> Y2 (f16), level2 -> global
#pragma unroll 1
    for (int pp = 0; pp < 2; ++pp) {
        int p = pp * 512 + tid;
        if (p < P_) {
            unsigned pk = pp == 0 ? pk_p0 : pk_p1;
            int o1 = (int)(pk & 2047u);
            int o2 = (int)((pk >> 11) & 2047u);
            uint4 ua0 = *(const uint4*)&emb2[o1];
            uint4 ua1 = *(const uint4*)&emb2[o1 + 8];
            uint4 uc0 = *(const uint4*)&emb2[o2];
            uint4 uc1 = *(const uint4*)&emb2[o2 + 8];
            float s = 0.f;
            uint4 y0, y1;
#define PKMUL(dst, a, c) {                                                    \
            half2v _a = __builtin_bit_cast(half2v, a);                        \
            half2v _c = __builtin_bit_cast(half2v, c);                        \
            half2v _y = _a * _c;                                              \
            dst = __builtin_bit_cast(unsigned, _y);                           \
            s = hdot2(a, c, s); }
            PKMUL(y0.x, ua0.x, uc0.x); PKMUL(y0.y, ua0.y, uc0.y);
            PKMUL(y0.z, ua0.z, uc0.z); PKMUL(y0.w, ua0.w, uc0.w);
            PKMUL(y1.x, ua1.x, uc1.x); PKMUL(y1.y, ua1.y, uc1.y);
            PKMUL(y1.z, ua1.z, uc1.z); PKMUL(y1.w, ua1.w, uc1.w);
#undef PKMUL
            *(uint4*)&Y2[p * YSTR] = y0;
            *(uint4*)&Y2[p * YSTR + 8] = y1;
            lrow[p] = __builtin_bit_cast(unsigned short, __float2half(s));
        }
    }
    __syncthreads();

    // P1: triples, branch-free: x = <Y2[p], emb2[i3]>, write straight to global
#pragma unroll 3
    for (int i = 0; i < 18; ++i) {
        int t = i * 512 + tid;
        if (t < T_) {
            unsigned pk = pkt[i];
            int yb = (int)(pk & 32767u);
            int o3 = (int)(pk >> 15);
            uint4 uy0 = *(const uint4*)&Y2[yb];
            uint4 uy1 = *(const uint4*)&Y2[yb + 8];
            uint4 ue0 = *(const uint4*)&emb2[o3];
            uint4 ue1 = *(const uint4*)&emb2[o3 + 8];
            float s = 0.f;
            s = hdot2(uy0.x, ue0.x, s); s = hdot2(uy0.y, ue0.y, s);
            s = hdot2(uy0.z, ue0.z, s); s = hdot2(uy0.w, ue0.w, s);
            s = hdot2(uy1.x, ue1.x, s); s = hdot2(uy1.y, ue1.y, s);
            s = hdot2(uy1.z, ue1.z, s);
            s = hdot2(uy1.w, ue1.w, s);
            lrow[P_ + t] = __builtin_bit_cast(unsigned short, __float2half(s));
        }
    }
}

// ---------- kernel 2: column partial stats over f16 levels (no atomics) -------------
__global__ __launch_bounds__(256) void stats2_k(const unsigned short* __restrict__ levels,
                                                float* __restrict__ psum,
                                                float* __restrict__ psumsq) {
    int col = blockIdx.x * 256 + threadIdx.x;
    if (col >= NC_) return;
    int sy = blockIdx.y;
    const unsigned short* p = levels + (size_t)(sy * (B_ / NSPLIT)) * LS2 + col;
    float a0 = 0.f, a1 = 0.f, a2 = 0.f, a3 = 0.f;
    float q0 = 0.f, q1 = 0.f, q2 = 0.f, q3 = 0.f;
#pragma unroll 4
    for (int r = 0; r < B_ / NSPLIT; r += 4) {
        float x0 = f16f(p[(size_t)(r + 0) * LS2]);
        float x1 = f16f(p[(size_t)(r + 1) * LS2]);
        float x2 = f16f(p[(size_t)(r + 2) * LS2]);
        float x3 = f16f(p[(size_t)(r + 3) * LS2]);
        a0 += x0; q0 += x0 * x0;
        a1 += x1; q1 += x1 * x1;
        a2 += x2; q2 += x2 * x2;
        a3 += x3; q3 += x3 * x3;
    }
    psum[sy * NC_ + col]   = (a0 + a1) + (a2 + a3);
    psumsq[sy * NC_ + col] = (q0 + q1) + (q2 + q3);
}

// ---------- kernel 3: BN finalize -> per-column scale + scalar C --------------------
__global__ __launch_bounds__(256) void finalize_k(const float* __restrict__ psum,
                                                  const float* __restrict__ psumsq,
                                                  const float* __restrict__ gamma2,
                                                  const float* __restrict__ beta2,
                                                  const float* __restrict__ gw2,
                                                  const float* __restrict__ gamma3,
                                                  const float* __restrict__ beta3,
                                                  const float* __restrict__ gw3,
                                                  float* __restrict__ scale,
                                                  float* __restrict__ Cacc) {
    int col = blockIdx.x * 256 + threadIdx.x;
    float c = 0.f;
    if (col < NC_) {
        float s1 = 0.f, s2 = 0.f;
#pragma unroll
        for (int sy = 0; sy < NSPLIT; ++sy) {
            s1 += psum[sy * NC_ + col];
            s2 += psumsq[sy * NC_ + col];
        }
        float mean = s1 * (1.0f / B_);
        float var  = s2 * (1.0f / B_) - mean * mean;
        float inv  = 1.0f / sqrtf(var + EPS_);
        float g, be, gw;
        if (col < P_) {
            g = gamma2[col]; be = beta2[col]; gw = gw2[col];
        } else {
            int t = col - P_;
            g = gamma3[t]; be = beta3[t]; gw = gw3[t];
        }
        scale[col] = gw * g * inv;
        c = gw * (be - g * inv * mean);
    }
    __shared__ float red[256];
    red[threadIdx.x] = c;
    __syncthreads();
    for (int s = 128; s > 0; s >>= 1) {
        if (threadIdx.x < s) red[threadIdx.x] += red[threadIdx.x + s];
        __syncthreads();
    }
    if (threadIdx.x == 0) atomicAdd(Cacc, red[0]);
}

// ---------- kernel 4: weighted row sum + linear term -> logits ----------------------
__global__ __launch_bounds__(256) void out_k(const unsigned short* __restrict__ levels,
                                             const float* __restrict__ scale,
                                             const int* __restrict__ feats,
                                             const float* __restrict__ w,
                                             const float* __restrict__ Cacc,
                                             const float* __restrict__ bias,
                                             float* __restrict__ out) {
    int b = blockIdx.x, tid = threadIdx.x;
    const uint4* lv = (const uint4*)(levels + (size_t)b * LS2);   // 8 f16 per uint4
    float acc = 0.f;
    // 9880 f16 = 1235 uint4 exactly
    for (int idx = tid; idx < 1235; idx += 256) {
        uint4 u = lv[idx];
        float4 sa = *(const float4*)&scale[idx * 8];
        float4 sb = *(const float4*)&scale[idx * 8 + 4];
        float2 f0 = __half22float2(__builtin_bit_cast(__half2, u.x));
        float2 f1 = __half22float2(__builtin_bit_cast(__half2, u.y));
        float2 f2 = __half22float2(__builtin_bit_cast(__half2, u.z));
        float2 f3 = __half22float2(__builtin_bit_cast(__half2, u.w));
        acc += sa.x * f0.x + sa.y * f0.y + sa.z * f1.x + sa.w * f1.y;
        acc += sb.x * f2.x + sb.y * f2.y + sb.z * f3.x + sb.w * f3.y;
    }
    if (tid < F_) acc += w[feats[b * F_ + tid]];   // linear term
    __shared__ float red[256];
    red[tid] = acc;
    __syncthreads();
    for (int s = 128; s > 0; s >>= 1) {
        if (tid < s) red[tid] += red[tid + s];
        __syncthreads();
    }
    if (tid == 0) out[b] = red[0] + Cacc[0] + bias[0];
}

// ---------- host launcher -----------------------------------------------------------
extern "C" void kernel_launch(void* const* d_in, const int* in_sizes, int n_in,
                              void* d_out, int out_size, void* d_ws, size_t ws_size,
                              hipStream_t stream) {
    const int*   feats  = (const int*)d_in[0];
    const float* w      = (const float*)d_in[1];
    const float* v      = (const float*)d_in[2];
    const float* bias   = (const float*)d_in[3];
    const float* gamma2 = (const float*)d_in[4];
    const float* beta2  = (const float*)d_in[5];
    const float* gw2    = (const float*)d_in[6];
    const float* gamma3 = (const float*)d_in[7];
    const float* beta3  = (const float*)d_in[8];
    const float* gw3    = (const float*)d_in[9];
    const int*   rows   = (const int*)d_in[10];
    const int*   cols   = (const int*)d_in[11];
    const int*   i1     = (const int*)d_in[12];
    const int*   i2     = (const int*)d_in[13];
    const int*   i3     = (const int*)d_in[14];
    float*       out    = (float*)d_out;
    float*       ws     = (float*)d_ws;

    // workspace layout (float offsets)
    float*          scale    = ws;                     // 9880
    float*          psum     = ws + 9880;              // 8*9880 = 79040
    float*          psumsq   = ws + 88920;             // 79040
    float*          Cacc     = ws + 167960;            // 1
    unsigned*       pidx     = (unsigned*)(ws + 168064);        // 9880 u32
    unsigned short* levels   = (unsigned short*)(ws + 177984);  // 1024*9920 f16 (~20.3 MB)

    prep_k<<<(NC_ + 255) / 256, 256, 0, stream>>>(rows, cols, i1, i2, i3, pidx, Cacc);
    levels_k<<<B_, 512, 0, stream>>>(feats, v, pidx, levels);
    stats2_k<<<dim3((NC_ + 255) / 256, NSPLIT), 256, 0, stream>>>(levels, psum, psumsq);
    finalize_k<<<(NC_ + 255) / 256, 256, 0, stream>>>(psum, psumsq,
                                                      gamma2, beta2, gw2,
                                                      gamma3, beta3, gw3, scale, Cacc);
    out_k<<<B_, 256, 0, stream>>>(levels, scale, feats, w, Cacc, bias, out);
}